// Round 4
// baseline (1050.680 us; speedup 1.0000x reference)
//
#include <hip/hip_runtime.h>
#include <stdint.h>

typedef float f32x4 __attribute__((ext_vector_type(4)));
typedef unsigned int uint;
typedef unsigned long long ull;
typedef unsigned short ushort_t;

#define NB 2048
#define NS 128
#define NI 8
#define NH 256
#define NG 1024   // 4*H
#define NK 50

#define A_SC 16.0f
#define W_SC 32.0f
#define SC_PROD 512.0f
#define INV_SC (1.0f/(A_SC*W_SC))

// IDM constants
#define DT_    0.1f
#define V_DES_ 12.64798288f
#define T_HW_  0.50284384f
#define A_MAX_ 0.10033688f
#define B_SAFE_ 4.98937183f
#define S0_    0.13082412f

// h stage in LDS: [32 rows][256 bytes]; granule XOR row&15 -> A-frag reads hit
// the 4-lanes-per-bank-pair floor. Identity: HADDR(row, kb*32+kgrp*8) ==
// HADDR(row, kgrp*8) ^ (kb<<5)  (XOR-addressable, 1 v_xor per read).
#define HADDR(row, boff) (((row) << 8) + (((((boff) >> 3) ^ ((row) & 15)) & 31) << 3) + ((boff) & 7))
// gate buffer: [32 rows][128 cols] f32, XOR column swizzle; pair-preserving.
#define GIDX(row, col) (((row) << 7) + ((col) ^ (((row) & 12) << 2)))

__device__ __forceinline__ uint8_t f2fp8(float v) {
    int r = __builtin_amdgcn_cvt_pk_fp8_f32(v, v, 0, false);
    return (uint8_t)(r & 0xff);
}
__device__ __forceinline__ float sigm(float x) { return 1.0f / (1.0f + __expf(-x)); }
__device__ __forceinline__ float tanh_f(float x) {
    x = fminf(fmaxf(x, -15.0f), 15.0f);
    float e = __expf(2.0f * x);
    return (e - 1.0f) / (e + 1.0f);
}

// ---------------- pre-pass kernels ----------------
__global__ void k_pack(const float* __restrict__ W, uint8_t* __restrict__ out,
                       int tiles, int KB, int Nsrc, int Ksrc) {
    int gid = blockIdx.x * 256 + threadIdx.x;
    int total = tiles * KB * 64;
    if (gid >= total) return;
    int lane = gid & 63;
    int kb   = (gid >> 6) % KB;
    int tile = gid / (64 * KB);
    int n = tile * 16 + (lane & 15);
    int kbase = kb * 32 + (lane >> 4) * 8;
    uint64_t wbits = 0;
    #pragma unroll
    for (int j = 0; j < 8; ++j) {
        int k = kbase + j;
        float v = (n < Nsrc && k < Ksrc) ? W[(size_t)n * Ksrc + k] * W_SC : 0.0f;
        wbits |= ((uint64_t)f2fp8(v)) << (8 * j);
    }
    *(uint64_t*)(out + (size_t)gid * 8) = wbits;
}

// biases pre-scaled by 512 so they add directly into the x512-domain gate acc
__global__ void k_bias(const float* __restrict__ bih0, const float* __restrict__ bhh0,
                       const float* __restrict__ bih1, const float* __restrict__ bhh1,
                       float* __restrict__ b0, float* __restrict__ b1) {
    int i = blockIdx.x * 256 + threadIdx.x;
    if (i < NG) b0[i] = (bih0[i] + bhh0[i]) * SC_PROD;
    else if (i < 2 * NG) b1[i - NG] = (bih1[i - NG] + bhh1[i - NG]) * SC_PROD;
}

__global__ void k_x8(const float* __restrict__ x, uint8_t* __restrict__ x8) {
    int i = blockIdx.x * 256 + threadIdx.x;
    if (i < NB * NS * NI) x8[i] = f2fp8(x[i] * A_SC);
}

// ---------------- weight-stationary LSTM, 512 WGs, 2 clusters/CU ----------------
// 512 WGs = 64 batch-groups (32 rows) x 8 gate-slices (32 units). Wave owns ONE
// 16x16 tile (gate, 16 units): 25 pinned B-frags = 50 VGPR. 2 WGs/CU so one
// cluster's MALL barrier hides under the other's compute.
__global__ __launch_bounds__(512, 4)
void k_lstm4(const uint8_t* __restrict__ x8,
             const uint8_t* __restrict__ Wih0P, const uint8_t* __restrict__ Whh0P,
             const uint8_t* __restrict__ Wih1P, const uint8_t* __restrict__ Whh1P,
             const uint8_t* __restrict__ WfcP,
             const float* __restrict__ bias0, const float* __restrict__ bias1,
             const float* __restrict__ bfc,
             uint8_t* __restrict__ h0g, uint8_t* __restrict__ h1g,
             uint* __restrict__ ctrs, float* __restrict__ out) {
    __shared__ uint8_t h0st[8192];   // h0[p-1], fp8, HADDR layout
    __shared__ uint8_t h1st[8192];   // h1[p-2]
    __shared__ float gA[4096];       // layer0 gates (32x128), GIDX, x512 domain
    __shared__ float gB[4096];       // layer1 gates

    const int tid  = threadIdx.x;
    const int w    = tid >> 6, lane = tid & 63;
    const int lrow = lane & 15, kgrp = lane >> 4;
    const int blk  = blockIdx.x;
    const int grp  = blk >> 3, slc = blk & 7;
    const int rowbase = grp * 32;
    const int g = w & 3, uh = w >> 2;          // wave: gate g, unit-half uh
    const int T = g * 16 + slc * 2 + uh;       // global 16-out tile index

    // ---- persistent weight fragments: 25 frags = 50 VGPR, pinned ----
    long wI0, wH0[8], wI1[8], wH1[8];
    wI0 = *(const long*)(Wih0P + ((size_t)T * 64 + lane) * 8);
    #pragma unroll
    for (int kb = 0; kb < 8; ++kb) {
        wH0[kb] = *(const long*)(Whh0P + (((size_t)T * 8 + kb) * 64 + lane) * 8);
        wI1[kb] = *(const long*)(Wih1P + (((size_t)T * 8 + kb) * 64 + lane) * 8);
        wH1[kb] = *(const long*)(Whh1P + (((size_t)T * 8 + kb) * 64 + lane) * 8);
    }
    asm volatile("" : "+v"(wI0));
    #pragma unroll
    for (int kb = 0; kb < 8; ++kb)
        asm volatile("" : "+v"(wH0[kb]), "+v"(wI1[kb]), "+v"(wH1[kb]));

    // staging bias (pre-scaled x512): one value per lane (col fixed)
    const int colw = g * 32 + uh * 16 + lrow;          // gate-stage col
    const float bw0 = bias0[g * 256 + slc * 32 + uh * 16 + lrow];
    const float bw1 = bias1[g * 256 + slc * 32 + uh * 16 + lrow];

    // nonlinearity mapping: thread -> (row, 2 adjacent units)
    const int nrow = tid >> 4;
    const int nu2  = (tid & 15) * 2;
    float c0v[2] = {0, 0}, c1v[2] = {0, 0};

    { int4 z = {0,0,0,0}; ((int4*)h0st)[tid] = z; ((int4*)h1st)[tid] = z; }
    __syncthreads();

    const int abase = HADDR(lrow, kgrp * 8);   // A-frag addr = (abase+rr*4096)^(kb<<5)
    uint8_t* const h0base = h0g + (size_t)grp * 16384;   // [parity][32][256]
    uint8_t* const h1base = h1g + (size_t)grp * 16384;
    uint* const myctr = ctrs + grp * 16;
    uint tgt = 0;

    for (int p = 0; p <= NS; ++p) {
        // ===== layer 0 MFMA (t=p): x_t@Wih0^T + h0[p-1]@Whh0^T, stage to gA =====
        if (p < NS) {
            f32x4 acc[2];
            acc[0] = (f32x4){0,0,0,0}; acc[1] = (f32x4){0,0,0,0};
            #pragma unroll
            for (int rr = 0; rr < 2; ++rr) {
                long a0 = 0;
                if (kgrp == 0) a0 = *(const long*)(x8 + (size_t)(rowbase + rr * 16 + lrow) * (NS * NI) + p * 8);
                acc[rr] = __builtin_amdgcn_mfma_f32_16x16x32_fp8_fp8(a0, wI0, acc[rr], 0, 0, 0);
                #pragma unroll
                for (int kb = 0; kb < 8; ++kb) {
                    long af = *(const long*)&h0st[(abase + rr * 4096) ^ (kb << 5)];
                    acc[rr] = __builtin_amdgcn_mfma_f32_16x16x32_fp8_fp8(af, wH0[kb], acc[rr], 0, 0, 0);
                }
            }
            #pragma unroll
            for (int rr = 0; rr < 2; ++rr)
            #pragma unroll
            for (int r = 0; r < 4; ++r) {
                int row = rr * 16 + kgrp * 4 + r;
                gA[GIDX(row, colw)] = acc[rr][r] + bw0;
            }
        }
        __syncthreads();   // S1: gates0 staged

        // ===== nonlin0 -> publish h0[p] (packed ushort, relaxed agent) =====
        if (p < NS) {
            float2 gq[4];
            #pragma unroll
            for (int q = 0; q < 4; ++q)
                gq[q] = *(float2*)&gA[GIDX(nrow, q * 32 + nu2)];
            float hh[2];
            #pragma unroll
            for (int u = 0; u < 2; ++u) {
                float iv = ((u ? gq[0].y : gq[0].x)) * INV_SC;
                float fv = ((u ? gq[1].y : gq[1].x)) * INV_SC;
                float gv = ((u ? gq[2].y : gq[2].x)) * INV_SC;
                float ov = ((u ? gq[3].y : gq[3].x)) * INV_SC;
                float c = sigm(fv) * c0v[u] + sigm(iv) * tanh_f(gv);
                c0v[u] = c;
                hh[u] = sigm(ov) * tanh_f(c);
            }
            int pk = __builtin_amdgcn_cvt_pk_fp8_f32(hh[0] * A_SC, hh[1] * A_SC, 0, false);
            __hip_atomic_store((ushort_t*)(h0base + (size_t)(p & 1) * 8192 + nrow * 256 + slc * 32 + nu2),
                               (ushort_t)(pk & 0xffff), __ATOMIC_RELAXED, __HIP_MEMORY_SCOPE_AGENT);
        }

        // ===== layer 1 MFMA (t=p-1): h0[p-1]@Wih1^T + h1[p-2]@Whh1^T -> gB =====
        if (p >= 1) {
            f32x4 acc[2];
            acc[0] = (f32x4){0,0,0,0}; acc[1] = (f32x4){0,0,0,0};
            #pragma unroll
            for (int rr = 0; rr < 2; ++rr) {
                #pragma unroll
                for (int kb = 0; kb < 8; ++kb) {
                    long af0 = *(const long*)&h0st[(abase + rr * 4096) ^ (kb << 5)];
                    acc[rr] = __builtin_amdgcn_mfma_f32_16x16x32_fp8_fp8(af0, wI1[kb], acc[rr], 0, 0, 0);
                    long af1 = *(const long*)&h1st[(abase + rr * 4096) ^ (kb << 5)];
                    acc[rr] = __builtin_amdgcn_mfma_f32_16x16x32_fp8_fp8(af1, wH1[kb], acc[rr], 0, 0, 0);
                }
            }
            #pragma unroll
            for (int rr = 0; rr < 2; ++rr)
            #pragma unroll
            for (int r = 0; r < 4; ++r) {
                int row = rr * 16 + kgrp * 4 + r;
                gB[GIDX(row, colw)] = acc[rr][r] + bw1;
            }
        }
        __syncthreads();   // S3: gates1 staged (gA reads also done before here)

        if (p >= 1) {
            float2 gq[4];
            #pragma unroll
            for (int q = 0; q < 4; ++q)
                gq[q] = *(float2*)&gB[GIDX(nrow, q * 32 + nu2)];
            float hh[2];
            #pragma unroll
            for (int u = 0; u < 2; ++u) {
                float iv = ((u ? gq[0].y : gq[0].x)) * INV_SC;
                float fv = ((u ? gq[1].y : gq[1].x)) * INV_SC;
                float gv = ((u ? gq[2].y : gq[2].x)) * INV_SC;
                float ov = ((u ? gq[3].y : gq[3].x)) * INV_SC;
                float c = sigm(fv) * c1v[u] + sigm(iv) * tanh_f(gv);
                c1v[u] = c;
                hh[u] = sigm(ov) * tanh_f(c);
            }
            int pk = __builtin_amdgcn_cvt_pk_fp8_f32(hh[0] * A_SC, hh[1] * A_SC, 0, false);
            __hip_atomic_store((ushort_t*)(h1base + (size_t)((p - 1) & 1) * 8192 + nrow * 256 + slc * 32 + nu2),
                               (ushort_t)(pk & 0xffff), __ATOMIC_RELAXED, __HIP_MEMORY_SCOPE_AGENT);
        }
        __syncthreads();   // S4: all publish stores drained (vmcnt(0) at barrier)

        // ===== cluster barrier: 8 WGs, relaxed agent atomics =====
        tgt += 8;
        if (tid == 0) {
            __hip_atomic_fetch_add(myctr, 1u, __ATOMIC_RELAXED, __HIP_MEMORY_SCOPE_AGENT);
            int gd = 0;
            while (__hip_atomic_load(myctr, __ATOMIC_RELAXED, __HIP_MEMORY_SCOPE_AGENT) < tgt) {
                __builtin_amdgcn_s_sleep(1);
                if (++gd >= (1 << 22)) break;
            }
        }
        __syncthreads();   // S5: barrier passed

        // ===== restage h0[p], h1[p-1]: MALL -> LDS =====
        {
            int rrow = tid & 31, seg = tid >> 5;   // 16 segs x 16B
            const ull* s0p = (const ull*)(h0base + (size_t)(p & 1) * 8192 + rrow * 256 + seg * 16);
            const ull* s1p = (const ull*)(h1base + (size_t)((p + 1) & 1) * 8192 + rrow * 256 + seg * 16);
            #pragma unroll
            for (int j = 0; j < 2; ++j) {
                ull q0 = __hip_atomic_load(s0p + j, __ATOMIC_RELAXED, __HIP_MEMORY_SCOPE_AGENT);
                ull q1 = __hip_atomic_load(s1p + j, __ATOMIC_RELAXED, __HIP_MEMORY_SCOPE_AGENT);
                *(ull*)&h0st[HADDR(rrow, seg * 16 + j * 8)] = q0;
                *(ull*)&h1st[HADDR(rrow, seg * 16 + j * 8)] = q1;
            }
        }
        __syncthreads();   // S6: stages ready for next phase
    }

    // ===== FC head: y = h1[127] @ Wfc^T + bfc (h1st holds h1[127]) =====
    if (slc < 4 && w < 2) {
        f32x4 a = (f32x4){0,0,0,0};
        #pragma unroll
        for (int kb = 0; kb < 8; ++kb) {
            long af = *(const long*)&h1st[HADDR(w * 16 + lrow, kb * 32 + kgrp * 8)];
            long bf = *(const long*)(WfcP + (((size_t)slc * 8 + kb) * 64 + lane) * 8);
            a = __builtin_amdgcn_mfma_f32_16x16x32_fp8_fp8(af, bf, a, 0, 0, 0);
        }
        int col = slc * 16 + lrow;
        if (col < NK) {
            float bb = bfc[col];
            #pragma unroll
            for (int r = 0; r < 4; ++r) {
                int row = rowbase + w * 16 + kgrp * 4 + r;
                out[(size_t)row * NK + col] = a[r] * INV_SC + bb;
            }
        }
    }
}

// ---------------- IDM rollout (exact fp32) ----------------
__global__ void k_idm(const float* __restrict__ x, const float* __restrict__ s0,
                      const float* __restrict__ vl, float* __restrict__ out) {
    int b = blockIdx.x * 256 + threadIdx.x;
    if (b >= NB) return;
    float v = x[(size_t)b * NS * NI + (NS - 1) * NI + 0];
    float s = s0[b];
    float vlead = vl[b];
    const float den = 2.0f * sqrtf(A_MAX_ * B_SAFE_) + 1e-6f;
    float* o = out + (size_t)NB * NK + (size_t)b * NK;
    #pragma unroll 1
    for (int k = 0; k < NK; ++k) {
        float dv = vlead - v;
        float sc = fmaxf(s, 1e-6f);
        float ss = fmaxf(S0_ + v * T_HW_ + v * dv / den, 0.0f);
        float a = A_MAX_ * (1.0f - v / V_DES_ - (ss / sc) * (ss / sc));
        v = fmaxf(v + DT_ * a, 0.0f);
        s = fmaxf(s + dv * DT_, 1e-6f);
        o[k] = v;
    }
}

// ---------------- launch ----------------
extern "C" void kernel_launch(void* const* d_in, const int* in_sizes, int n_in,
                              void* d_out, int out_size, void* d_ws, size_t ws_size,
                              hipStream_t stream) {
    const float* x    = (const float*)d_in[0];
    const float* s0   = (const float*)d_in[1];
    const float* vl   = (const float*)d_in[2];
    const float* Wih0 = (const float*)d_in[3];
    const float* Whh0 = (const float*)d_in[4];
    const float* bih0 = (const float*)d_in[5];
    const float* bhh0 = (const float*)d_in[6];
    const float* Wih1 = (const float*)d_in[7];
    const float* Whh1 = (const float*)d_in[8];
    const float* bih1 = (const float*)d_in[9];
    const float* bhh1 = (const float*)d_in[10];
    const float* Wfc  = (const float*)d_in[11];
    const float* bfc  = (const float*)d_in[12];
    float* out = (float*)d_out;

    uint8_t* ws = (uint8_t*)d_ws;
    size_t off = 0;
    auto alloc = [&](size_t n) { uint8_t* p = ws + off; off += (n + 255) & ~(size_t)255; return p; };
    uint8_t* Wih0P = alloc(64 * 1 * 64 * 8);
    uint8_t* Whh0P = alloc(64 * 8 * 64 * 8);
    uint8_t* Wih1P = alloc(64 * 8 * 64 * 8);
    uint8_t* Whh1P = alloc(64 * 8 * 64 * 8);
    uint8_t* WfcP  = alloc(4 * 8 * 64 * 8);
    float* b0 = (float*)alloc(NG * 4);
    float* b1 = (float*)alloc(NG * 4);
    uint8_t* x8 = alloc((size_t)NB * NS * NI);
    // h exchange zone (memset each launch): h0g | h1g | ctrs, contiguous
    uint8_t* h0g = alloc((size_t)64 * 16384);
    uint8_t* h1g = alloc((size_t)64 * 16384);
    uint*    ctrs = (uint*)alloc(64 * 64);
    size_t hz = (size_t)(((uint8_t*)ctrs + 64 * 64) - h0g);

    k_pack<<<(64 * 1 * 64 + 255) / 256, 256, 0, stream>>>(Wih0, Wih0P, 64, 1, NG, NI);
    k_pack<<<(64 * 8 * 64 + 255) / 256, 256, 0, stream>>>(Whh0, Whh0P, 64, 8, NG, NH);
    k_pack<<<(64 * 8 * 64 + 255) / 256, 256, 0, stream>>>(Wih1, Wih1P, 64, 8, NG, NH);
    k_pack<<<(64 * 8 * 64 + 255) / 256, 256, 0, stream>>>(Whh1, Whh1P, 64, 8, NG, NH);
    k_pack<<<(4 * 8 * 64 + 255) / 256, 256, 0, stream>>>(Wfc, WfcP, 4, 8, NK, NH);
    k_bias<<<(2 * NG + 255) / 256, 256, 0, stream>>>(bih0, bhh0, bih1, bhh1, b0, b1);
    k_x8<<<(NB * NS * NI + 255) / 256, 256, 0, stream>>>(x, x8);
    hipMemsetAsync(h0g, 0, hz, stream);

    void* kargs[] = { (void*)&x8, (void*)&Wih0P, (void*)&Whh0P, (void*)&Wih1P, (void*)&Whh1P,
                      (void*)&WfcP, (void*)&b0, (void*)&b1, (void*)&bfc,
                      (void*)&h0g, (void*)&h1g, (void*)&ctrs, (void*)&out };
    hipError_t ce = hipLaunchCooperativeKernel((const void*)k_lstm4, dim3(512), dim3(512), kargs, 0, stream);
    if (ce != hipSuccess) {
        k_lstm4<<<512, 512, 0, stream>>>(x8, Wih0P, Whh0P, Wih1P, Whh1P, WfcP, b0, b1, bfc, h0g, h1g, ctrs, out);
    }
    k_idm<<<(NB + 255) / 256, 256, 0, stream>>>(x, s0, vl, out);
}